// Round 1
// baseline (1454.659 us; speedup 1.0000x reference)
//
#include <hip/hip_runtime.h>

// ---------------- kernels ----------------

__global__ void k_zero_f32(float* __restrict__ p, long n) {
    long i = (long)blockIdx.x * blockDim.x + threadIdx.x;
    if (i < n) p[i] = 0.0f;
}

// degree count: deg[col[e]] += 1
__global__ void k_count_deg(const int* __restrict__ col, int E, float* __restrict__ deg) {
    int e = blockIdx.x * blockDim.x + threadIdx.x;
    if (e < E) atomicAdd(&deg[col[e]], 1.0f);
}

__global__ void k_finish_dinv(float* __restrict__ deg, int N) {
    int i = blockIdx.x * blockDim.x + threadIdx.x;
    if (i < N) deg[i] = rsqrtf(deg[i] + 1.0f);
}

// P[n,m] = sum_k X[n,k] * W[k,m]
__global__ void k_gemm(const float* __restrict__ X, const float* __restrict__ W,
                       float* __restrict__ P, int N, int K, int M) {
    long idx = (long)blockIdx.x * blockDim.x + threadIdx.x;
    long total = (long)N * M;
    if (idx >= total) return;
    int n = (int)(idx / M);
    int m = (int)(idx - (long)n * M);
    const float* xr = X + (long)n * K;
    float acc = 0.0f;
#pragma unroll 8
    for (int k = 0; k < K; ++k) acc += xr[k] * W[k * M + m];
    P[idx] = acc;
}

// G[col[e], f] += P[row[e], f] * dinv[row]*dinv[col]
__global__ void k_scatter(const int* __restrict__ row, const int* __restrict__ col, int E,
                          const float* __restrict__ P, const float* __restrict__ dinv,
                          float* __restrict__ G, int M) {
    long idx = (long)blockIdx.x * blockDim.x + threadIdx.x;
    long total = (long)E * M;
    if (idx >= total) return;
    int e = (int)(idx / M);
    int f = (int)(idx - (long)e * M);
    int r = row[e];
    int c = col[e];
    float w = dinv[r] * dinv[c];
    atomicAdd(&G[(long)c * M + f], P[(long)r * M + f] * w);
}

// G[n,f] = (G[n,f] + dinv[n]^2 * P[n,f] + b[f]) [relu]
__global__ void k_combine(const float* __restrict__ P, const float* __restrict__ dinv,
                          const float* __restrict__ b, float* __restrict__ G,
                          int N, int M, int do_relu) {
    long idx = (long)blockIdx.x * blockDim.x + threadIdx.x;
    long total = (long)N * M;
    if (idx >= total) return;
    int n = (int)(idx / M);
    int f = (int)(idx - (long)n * M);
    float d = dinv[n];
    float v = G[idx] + d * d * P[idx] + b[f];
    if (do_relu) v = fmaxf(v, 0.0f);
    G[idx] = v;
}

// sums[batch[n], f] += G[n,f]; cnts[batch[n]] += 1 (once per node)
__global__ void k_pool(const float* __restrict__ G, const int* __restrict__ batch,
                       int N, int M, float* __restrict__ sums, float* __restrict__ cnts) {
    long idx = (long)blockIdx.x * blockDim.x + threadIdx.x;
    long total = (long)N * M;
    if (idx >= total) return;
    int n = (int)(idx / M);
    int f = (int)(idx - (long)n * M);
    int g = batch[n];
    atomicAdd(&sums[(long)g * M + f], G[idx]);
    if (f == 0) atomicAdd(&cnts[g], 1.0f);
}

// out[g,j] = sum_f (sums[g,f]/max(cnt,1)) * Wl[f,j] + bl[j]
__global__ void k_final(const float* __restrict__ sums, const float* __restrict__ cnts,
                        const float* __restrict__ Wl, const float* __restrict__ bl,
                        float* __restrict__ out, int Gn, int F, int C) {
    int idx = blockIdx.x * blockDim.x + threadIdx.x;
    if (idx >= Gn * C) return;
    int g = idx / C;
    int j = idx - g * C;
    float inv = 1.0f / fmaxf(cnts[g], 1.0f);
    float acc = bl[j];
    for (int f = 0; f < F; ++f) acc += sums[g * F + f] * inv * Wl[f * C + j];
    out[idx] = acc;
}

// ---------------- launch ----------------

extern "C" void kernel_launch(void* const* d_in, const int* in_sizes, int n_in,
                              void* d_out, int out_size, void* d_ws, size_t ws_size,
                              hipStream_t stream) {
    const float* x  = (const float*)d_in[0];
    const int*   ei = (const int*)d_in[1];
    const int*   batch = (const int*)d_in[2];
    const float* W1 = (const float*)d_in[3];
    const float* b1 = (const float*)d_in[4];
    const float* W2 = (const float*)d_in[5];
    const float* b2 = (const float*)d_in[6];
    const float* W3 = (const float*)d_in[7];
    const float* b3 = (const float*)d_in[8];
    const float* Wl = (const float*)d_in[9];
    const float* bl = (const float*)d_in[10];

    const int N  = in_sizes[2];          // 50000 nodes
    const int E  = in_sizes[1] / 2;      // 800000 edges
    const int C  = in_sizes[10];         // 10 classes
    const int Gn = out_size / C;         // 512 graphs
    const int F1 = in_sizes[4];          // 128
    const int F2 = in_sizes[6];          // 128
    const int F3 = in_sizes[8];          // 64
    const int K0 = in_sizes[0] / N;      // 64 input features

    const int* row = ei;
    const int* col = ei + E;

    // workspace layout (floats)
    float* ws   = (float*)d_ws;
    float* dinv = ws;                        // N
    float* P    = dinv + N;                  // N*128
    float* G    = P + (long)N * 128;         // N*128
    float* sums = G + (long)N * 128;         // Gn*F3
    float* cnts = sums + (long)Gn * F3;      // Gn

    const int B = 256;
    auto blocks = [](long n, int b) { return (int)((n + b - 1) / b); };

    // --- degrees ---
    k_zero_f32<<<blocks(N, B), B, 0, stream>>>(dinv, N);
    k_count_deg<<<blocks(E, B), B, 0, stream>>>(col, E, dinv);
    k_finish_dinv<<<blocks(N, B), B, 0, stream>>>(dinv, N);

    // --- layer 1: x[N,K0] @ W1[K0,F1] ---
    k_gemm<<<blocks((long)N * F1, B), B, 0, stream>>>(x, W1, P, N, K0, F1);
    k_zero_f32<<<blocks((long)N * F1, B), B, 0, stream>>>(G, (long)N * F1);
    k_scatter<<<blocks((long)E * F1, B), B, 0, stream>>>(row, col, E, P, dinv, G, F1);
    k_combine<<<blocks((long)N * F1, B), B, 0, stream>>>(P, dinv, b1, G, N, F1, 1);

    // --- layer 2: G[N,F1] @ W2[F1,F2] ---
    k_gemm<<<blocks((long)N * F2, B), B, 0, stream>>>(G, W2, P, N, F1, F2);
    k_zero_f32<<<blocks((long)N * F2, B), B, 0, stream>>>(G, (long)N * F2);
    k_scatter<<<blocks((long)E * F2, B), B, 0, stream>>>(row, col, E, P, dinv, G, F2);
    k_combine<<<blocks((long)N * F2, B), B, 0, stream>>>(P, dinv, b2, G, N, F2, 1);

    // --- layer 3: G[N,F2] @ W3[F2,F3] (no relu) ---
    k_gemm<<<blocks((long)N * F3, B), B, 0, stream>>>(G, W3, P, N, F2, F3);
    k_zero_f32<<<blocks((long)N * F3, B), B, 0, stream>>>(G, (long)N * F3);
    k_scatter<<<blocks((long)E * F3, B), B, 0, stream>>>(row, col, E, P, dinv, G, F3);
    k_combine<<<blocks((long)N * F3, B), B, 0, stream>>>(P, dinv, b3, G, N, F3, 0);

    // --- pool + final linear ---
    k_zero_f32<<<blocks((long)Gn * F3 + Gn, B), B, 0, stream>>>(sums, (long)Gn * F3 + Gn);
    k_pool<<<blocks((long)N * F3, B), B, 0, stream>>>(G, batch, N, F3, sums, cnts);
    k_final<<<blocks(Gn * C, B), B, 0, stream>>>(sums, cnts, Wl, bl, (float*)d_out, Gn, F3, C);
}

// Round 2
// 975.854 us; speedup vs baseline: 1.4907x; 1.4907x over previous
//
#include <hip/hip_runtime.h>

// ---------------- kernels ----------------

__global__ void k_zero_i32(int* __restrict__ p, int n) {
    int i = blockIdx.x * blockDim.x + threadIdx.x;
    if (i < n) p[i] = 0;
}

// cnt[col[e]] += 1
__global__ void k_count(const int* __restrict__ col, int E, int* __restrict__ cnt) {
    int e = blockIdx.x * blockDim.x + threadIdx.x;
    if (e < E) atomicAdd(&cnt[col[e]], 1);
}

// single-block exclusive scan over cnt[0..N) -> starts[0..N]
__global__ void k_scan(const int* __restrict__ cnt, int* __restrict__ starts, int N) {
    __shared__ int smem[1024];
    __shared__ int carry;
    if (threadIdx.x == 0) carry = 0;
    __syncthreads();
    for (int base = 0; base < N; base += 1024) {
        int i = base + threadIdx.x;
        int v = (i < N) ? cnt[i] : 0;
        smem[threadIdx.x] = v;
        __syncthreads();
        for (int off = 1; off < 1024; off <<= 1) {
            int t = (threadIdx.x >= off) ? smem[threadIdx.x - off] : 0;
            __syncthreads();
            smem[threadIdx.x] += t;
            __syncthreads();
        }
        int incl = smem[threadIdx.x];
        if (i < N) starts[i] = carry + incl - v;   // exclusive
        __syncthreads();
        if (threadIdx.x == 1023) carry += smem[1023];
        __syncthreads();
    }
    if (threadIdx.x == 0) starts[N] = carry;
}

// dinv[i] = rsqrt(indeg + 1)
__global__ void k_dinv(const int* __restrict__ starts, float* __restrict__ dinv, int N) {
    int i = blockIdx.x * blockDim.x + threadIdx.x;
    if (i < N) dinv[i] = rsqrtf((float)(starts[i + 1] - starts[i]) + 1.0f);
}

// csr[starts[c] + cursor[c]++] = row[e]
__global__ void k_fill(const int* __restrict__ row, const int* __restrict__ col, int E,
                       const int* __restrict__ starts, int* __restrict__ cursor,
                       int* __restrict__ csr) {
    int e = blockIdx.x * blockDim.x + threadIdx.x;
    if (e >= E) return;
    int c = col[e];
    int pos = starts[c] + atomicAdd(&cursor[c], 1);
    csr[pos] = row[e];
}

// P[n,m] = sum_k X[n,k] * W[k,m]
__global__ void k_gemm(const float* __restrict__ X, const float* __restrict__ W,
                       float* __restrict__ P, int N, int K, int M) {
    long idx = (long)blockIdx.x * blockDim.x + threadIdx.x;
    long total = (long)N * M;
    if (idx >= total) return;
    int n = (int)(idx / M);
    int m = (int)(idx - (long)n * M);
    const float* xr = X + (long)n * K;
    float acc = 0.0f;
#pragma unroll 8
    for (int k = 0; k < K; ++k) acc += xr[k] * W[k * M + m];
    P[idx] = acc;
}

// H[c,f] = relu?( dinv[c] * sum_{r in nbr(c)} P[r,f]*dinv[r] + dinv[c]^2*P[c,f] + b[f] )
__global__ void k_aggregate(const float* __restrict__ P, const int* __restrict__ starts,
                            const int* __restrict__ csr, const float* __restrict__ dinv,
                            const float* __restrict__ b, float* __restrict__ H,
                            int N, int M, int do_relu) {
    int npb = blockDim.x / M;            // nodes per block
    int local = threadIdx.x / M;
    int f = threadIdx.x - local * M;
    int c = blockIdx.x * npb + local;
    if (c >= N) return;
    int s = starts[c], e = starts[c + 1];
    float acc = 0.0f;
    for (int i = s; i < e; ++i) {
        int r = csr[i];
        acc += P[(long)r * M + f] * dinv[r];
    }
    float dc = dinv[c];
    float v = dc * acc + dc * dc * P[(long)c * M + f] + b[f];
    if (do_relu) v = fmaxf(v, 0.0f);
    H[(long)c * M + f] = v;
}

__device__ __forceinline__ int lower_bound_i(const int* __restrict__ a, int n, int key) {
    int lo = 0, hi = n;
    while (lo < hi) { int mid = (lo + hi) >> 1; if (a[mid] < key) lo = mid + 1; else hi = mid; }
    return lo;
}

// pooled[g,f] = mean over nodes of graph g (batch sorted) of H[n,f]
__global__ void k_pool(const float* __restrict__ H, const int* __restrict__ batch,
                       int N, int M, float* __restrict__ pooled) {
    int g = blockIdx.x;
    int f = threadIdx.x;       // blockDim.x == M
    int lo = lower_bound_i(batch, N, g);
    int hi = lower_bound_i(batch, N, g + 1);
    float acc = 0.0f;
    for (int n = lo; n < hi; ++n) acc += H[(long)n * M + f];
    float inv = 1.0f / fmaxf((float)(hi - lo), 1.0f);
    pooled[(long)g * M + f] = acc * inv;
}

// out[g,j] = sum_f pooled[g,f] * Wl[f,j] + bl[j]
__global__ void k_final(const float* __restrict__ pooled, const float* __restrict__ Wl,
                        const float* __restrict__ bl, float* __restrict__ out,
                        int Gn, int F, int C) {
    int idx = blockIdx.x * blockDim.x + threadIdx.x;
    if (idx >= Gn * C) return;
    int g = idx / C;
    int j = idx - g * C;
    float acc = bl[j];
    for (int f = 0; f < F; ++f) acc += pooled[g * F + f] * Wl[f * C + j];
    out[idx] = acc;
}

// ---------------- launch ----------------

extern "C" void kernel_launch(void* const* d_in, const int* in_sizes, int n_in,
                              void* d_out, int out_size, void* d_ws, size_t ws_size,
                              hipStream_t stream) {
    const float* x  = (const float*)d_in[0];
    const int*   ei = (const int*)d_in[1];
    const int*   batch = (const int*)d_in[2];
    const float* W1 = (const float*)d_in[3];
    const float* b1 = (const float*)d_in[4];
    const float* W2 = (const float*)d_in[5];
    const float* b2 = (const float*)d_in[6];
    const float* W3 = (const float*)d_in[7];
    const float* b3 = (const float*)d_in[8];
    const float* Wl = (const float*)d_in[9];
    const float* bl = (const float*)d_in[10];

    const int N  = in_sizes[2];          // 50000
    const int E  = in_sizes[1] / 2;      // 800000
    const int C  = in_sizes[10];         // 10
    const int Gn = out_size / C;         // 512
    const int F1 = in_sizes[4];          // 128
    const int F2 = in_sizes[6];          // 128
    const int F3 = in_sizes[8];          // 64
    const int K0 = in_sizes[0] / N;      // 64

    const int* row = ei;
    const int* col = ei + E;

    // workspace layout
    int* cnt    = (int*)d_ws;                 // N
    int* starts = cnt + N;                    // N+1
    int* cursor = starts + N + 1;             // N
    int* csr    = cursor + N;                 // E
    float* dinv = (float*)(csr + E);          // N
    float* P    = dinv + N;                   // N*128
    float* H    = P + (long)N * 128;          // N*128
    float* pooled = H + (long)N * 128;        // Gn*F3

    const int B = 256;
    auto blocks = [](long n, int b) { return (int)((n + b - 1) / b); };

    // --- build CSR (destination-sorted adjacency) ---
    k_zero_i32<<<blocks(2 * N, B), B, 0, stream>>>(cnt, N);   // zeros cnt only
    k_zero_i32<<<blocks(N, B), B, 0, stream>>>(cursor, N);
    k_count<<<blocks(E, B), B, 0, stream>>>(col, E, cnt);
    k_scan<<<1, 1024, 0, stream>>>(cnt, starts, N);
    k_dinv<<<blocks(N, B), B, 0, stream>>>(starts, dinv, N);
    k_fill<<<blocks(E, B), B, 0, stream>>>(row, col, E, starts, cursor, csr);

    // --- layer 1 ---
    k_gemm<<<blocks((long)N * F1, B), B, 0, stream>>>(x, W1, P, N, K0, F1);
    k_aggregate<<<blocks(N, B / F1) , B, 0, stream>>>(P, starts, csr, dinv, b1, H, N, F1, 1);

    // --- layer 2 ---
    k_gemm<<<blocks((long)N * F2, B), B, 0, stream>>>(H, W2, P, N, F1, F2);
    k_aggregate<<<blocks(N, B / F2), B, 0, stream>>>(P, starts, csr, dinv, b2, H, N, F2, 1);

    // --- layer 3 ---
    k_gemm<<<blocks((long)N * F3, B), B, 0, stream>>>(H, W3, P, N, F2, F3);
    k_aggregate<<<blocks(N, B / F3), B, 0, stream>>>(P, starts, csr, dinv, b3, H, N, F3, 0);

    // --- pool + final ---
    k_pool<<<Gn, F3, 0, stream>>>(H, batch, N, F3, pooled);
    k_final<<<blocks(Gn * C, B), B, 0, stream>>>(pooled, Wl, bl, (float*)d_out, Gn, F3, C);
}

// Round 4
// 444.571 us; speedup vs baseline: 3.2720x; 2.1950x over previous
//
#include <hip/hip_runtime.h>

// ---------------- utility kernels ----------------

__global__ void k_zero_i32(int* __restrict__ p, int n) {
    int i = blockIdx.x * blockDim.x + threadIdx.x;
    if (i < n) p[i] = 0;
}

__global__ void k_count(const int* __restrict__ col, int E, int* __restrict__ cnt) {
    int e = blockIdx.x * blockDim.x + threadIdx.x;
    if (e < E) atomicAdd(&cnt[col[e]], 1);
}

// single-block scan, wave-shfl based: starts = exclusive_scan(cnt), starts[N]=E
__global__ void k_scan(const int* __restrict__ cnt, int* __restrict__ starts, int N) {
    __shared__ int wsum[16];
    __shared__ int carry_s;
    const int t = threadIdx.x;
    const int lane = t & 63;
    const int w = t >> 6;
    if (t == 0) carry_s = 0;
    __syncthreads();
    for (int base = 0; base < N; base += 1024) {
        int i = base + t;
        int v = (i < N) ? cnt[i] : 0;
        int s = v;
        #pragma unroll
        for (int off = 1; off < 64; off <<= 1) {
            int u = __shfl_up(s, off, 64);
            if (lane >= off) s += u;
        }
        if (lane == 63) wsum[w] = s;
        __syncthreads();
        if (t == 0) {
            int run = carry_s;
            #pragma unroll
            for (int j = 0; j < 16; ++j) { int tmp = wsum[j]; wsum[j] = run; run += tmp; }
            carry_s = run;
        }
        __syncthreads();
        if (i < N) starts[i] = wsum[w] + s - v;   // exclusive
        __syncthreads();
    }
    if (t == 0) starts[N] = carry_s;
}

__global__ void k_dinv(const int* __restrict__ starts, float* __restrict__ dinv, int N) {
    int i = blockIdx.x * blockDim.x + threadIdx.x;
    if (i < N) dinv[i] = rsqrtf((float)(starts[i + 1] - starts[i]) + 1.0f);
}

__global__ void k_fill(const int* __restrict__ row, const int* __restrict__ col, int E,
                       const int* __restrict__ starts, int* __restrict__ cursor,
                       int* __restrict__ csr) {
    int e = blockIdx.x * blockDim.x + threadIdx.x;
    if (e >= E) return;
    int c = col[e];
    int pos = starts[c] + atomicAdd(&cursor[c], 1);
    csr[pos] = row[e];
}

// ---------------- tiled fp32 GEMM ----------------
// P[n,m] = sum_k X[n,k] * W[k,m]; thread tile: TN=4 nodes x TM=8 outputs
// (m columns tm*4..+3 and M/2+tm*4..+3 -> conflict-free LDS reads/stores)

template<int K, int M, int BN>
__global__ void k_gemm_t(const float* __restrict__ X, const float* __restrict__ W,
                         float* __restrict__ P, int N) {
    constexpr int TM = 8;
    constexpr int TN = 4;
    constexpr int TMN = M / TM;          // threads along m
    constexpr int TNN = BN / TN;         // threads along n
    constexpr int NT = TMN * TNN;        // block size
    constexpr int KC = 64;               // K chunk
    constexpr int MH = M / 2;
    constexpr int XLD = KC + 1;          // padded X row (floats)
    __shared__ float Wl[KC * M];
    __shared__ float Xl[BN * XLD];
    const int t = threadIdx.x;
    const int tm = t % TMN;
    const int tn = t / TMN;
    const int n0 = blockIdx.x * BN;
    float acc[TN][TM] = {};
    for (int k0 = 0; k0 < K; k0 += KC) {
        // stage W chunk (contiguous KC*M floats), coalesced float4
        #pragma unroll
        for (int i = t * 4; i < KC * M; i += NT * 4)
            *(float4*)&Wl[i] = *(const float4*)&W[(long)k0 * M + i];
        // stage X tile as [n][k] with +1 pad
        {
            const int kq = t % (KC / 4);
            const int nl0 = t / (KC / 4);
            constexpr int NPN = NT / (KC / 4);    // nodes covered per pass
            #pragma unroll
            for (int p = 0; p < BN / NPN; ++p) {
                int n = nl0 + p * NPN;
                int gn = n0 + n;
                float4 v = make_float4(0.f, 0.f, 0.f, 0.f);
                if (gn < N) v = *(const float4*)&X[(long)gn * K + k0 + kq * 4];
                float* xr = &Xl[n * XLD + kq * 4];
                xr[0] = v.x; xr[1] = v.y; xr[2] = v.z; xr[3] = v.w;
            }
        }
        __syncthreads();
        #pragma unroll 4
        for (int k = 0; k < KC; ++k) {
            float4 w0 = *(float4*)&Wl[k * M + tm * 4];
            float4 w1 = *(float4*)&Wl[k * M + MH + tm * 4];
            float xs[TN];
            #pragma unroll
            for (int i = 0; i < TN; ++i) xs[i] = Xl[(tn * TN + i) * XLD + k];
            #pragma unroll
            for (int i = 0; i < TN; ++i) {
                acc[i][0] += xs[i] * w0.x;
                acc[i][1] += xs[i] * w0.y;
                acc[i][2] += xs[i] * w0.z;
                acc[i][3] += xs[i] * w0.w;
                acc[i][4] += xs[i] * w1.x;
                acc[i][5] += xs[i] * w1.y;
                acc[i][6] += xs[i] * w1.z;
                acc[i][7] += xs[i] * w1.w;
            }
        }
        __syncthreads();
    }
    #pragma unroll
    for (int i = 0; i < TN; ++i) {
        int gn = n0 + tn * TN + i;
        if (gn < N) {
            float4 a0 = make_float4(acc[i][0], acc[i][1], acc[i][2], acc[i][3]);
            float4 a1 = make_float4(acc[i][4], acc[i][5], acc[i][6], acc[i][7]);
            *(float4*)&P[(long)gn * M + tm * 4] = a0;
            *(float4*)&P[(long)gn * M + MH + tm * 4] = a1;
        }
    }
}

// generic fallback (unexpected shapes)
__global__ void k_gemm_naive(const float* __restrict__ X, const float* __restrict__ W,
                             float* __restrict__ P, int N, int K, int M) {
    long idx = (long)blockIdx.x * blockDim.x + threadIdx.x;
    long total = (long)N * M;
    if (idx >= total) return;
    int n = (int)(idx / M);
    int m = (int)(idx - (long)n * M);
    const float* xr = X + (long)n * K;
    float acc = 0.0f;
    for (int k = 0; k < K; ++k) acc += xr[k] * W[k * M + m];
    P[idx] = acc;
}

// ---------------- aggregation (gather, float4) ----------------
// H[c,f] = relu?( dinv[c]*sum_{r in nbr(c)} P[r,f]*dinv[r] + dinv[c]^2*P[c,f] + b[f] )

template<int M>
__global__ void k_aggregate4(const float* __restrict__ P, const int* __restrict__ starts,
                             const int* __restrict__ csr, const float* __restrict__ dinv,
                             const float* __restrict__ b, float* __restrict__ H,
                             int N, int do_relu) {
    constexpr int TPN = M / 4;              // threads per node
    constexpr int NPB = 256 / TPN;          // nodes per block
    int local = threadIdx.x / TPN;
    int fq = threadIdx.x % TPN;
    int c = blockIdx.x * NPB + local;
    if (c >= N) return;
    int s = starts[c], e = starts[c + 1];
    float4 acc = make_float4(0.f, 0.f, 0.f, 0.f);
    for (int i = s; i < e; ++i) {
        int r = csr[i];
        float dr = dinv[r];
        float4 p = *(const float4*)&P[(long)r * M + fq * 4];
        acc.x += p.x * dr; acc.y += p.y * dr; acc.z += p.z * dr; acc.w += p.w * dr;
    }
    float dc = dinv[c];
    float dc2 = dc * dc;
    float4 ps = *(const float4*)&P[(long)c * M + fq * 4];
    float4 bb = *(const float4*)&b[fq * 4];
    float4 v;
    v.x = dc * acc.x + dc2 * ps.x + bb.x;
    v.y = dc * acc.y + dc2 * ps.y + bb.y;
    v.z = dc * acc.z + dc2 * ps.z + bb.z;
    v.w = dc * acc.w + dc2 * ps.w + bb.w;
    if (do_relu) {
        v.x = fmaxf(v.x, 0.f); v.y = fmaxf(v.y, 0.f);
        v.z = fmaxf(v.z, 0.f); v.w = fmaxf(v.w, 0.f);
    }
    *(float4*)&H[(long)c * M + fq * 4] = v;
}

// ---------------- pooling + classifier ----------------

__device__ __forceinline__ int lower_bound_i(const int* __restrict__ a, int n, int key) {
    int lo = 0, hi = n;
    while (lo < hi) { int mid = (lo + hi) >> 1; if (a[mid] < key) lo = mid + 1; else hi = mid; }
    return lo;
}

__global__ void k_pool(const float* __restrict__ H, const int* __restrict__ batch,
                       int N, int M, float* __restrict__ pooled) {
    int g = blockIdx.x;
    int f = threadIdx.x;       // blockDim.x == M
    int lo = lower_bound_i(batch, N, g);
    int hi = lower_bound_i(batch, N, g + 1);
    float acc = 0.0f;
    for (int n = lo; n < hi; ++n) acc += H[(long)n * M + f];
    float inv = 1.0f / fmaxf((float)(hi - lo), 1.0f);
    pooled[(long)g * M + f] = acc * inv;
}

__global__ void k_final(const float* __restrict__ pooled, const float* __restrict__ Wl,
                        const float* __restrict__ bl, float* __restrict__ out,
                        int Gn, int F, int C) {
    int idx = blockIdx.x * blockDim.x + threadIdx.x;
    if (idx >= Gn * C) return;
    int g = idx / C;
    int j = idx - g * C;
    float acc = bl[j];
    for (int f = 0; f < F; ++f) acc += pooled[g * F + f] * Wl[f * C + j];
    out[idx] = acc;
}

// ---------------- launch ----------------

extern "C" void kernel_launch(void* const* d_in, const int* in_sizes, int n_in,
                              void* d_out, int out_size, void* d_ws, size_t ws_size,
                              hipStream_t stream) {
    const float* x  = (const float*)d_in[0];
    const int*   ei = (const int*)d_in[1];
    const int*   batch = (const int*)d_in[2];
    const float* W1 = (const float*)d_in[3];
    const float* b1 = (const float*)d_in[4];
    const float* W2 = (const float*)d_in[5];
    const float* b2 = (const float*)d_in[6];
    const float* W3 = (const float*)d_in[7];
    const float* b3 = (const float*)d_in[8];
    const float* Wl = (const float*)d_in[9];
    const float* bl = (const float*)d_in[10];

    const int N  = in_sizes[2];          // 50000
    const int E  = in_sizes[1] / 2;      // 800000
    const int C  = in_sizes[10];         // 10
    const int Gn = out_size / C;         // 512
    const int F1 = in_sizes[4];          // 128
    const int F2 = in_sizes[6];          // 128
    const int F3 = in_sizes[8];          // 64
    const int K0 = in_sizes[0] / N;      // 64

    const int* row = ei;
    const int* col = ei + E;

    // workspace layout
    int* cnt    = (int*)d_ws;                 // N
    int* starts = cnt + N;                    // N+1
    int* cursor = starts + N + 1;             // N
    int* csr    = cursor + N;                 // E
    float* dinv = (float*)(csr + E);          // N
    float* P    = dinv + N;                   // N*128
    float* H    = P + (long)N * 128;          // N*128
    float* pooled = H + (long)N * 128;        // Gn*F3

    const int B = 256;
    auto blocks = [](long n, int b) { return (int)((n + b - 1) / b); };

    // --- build CSR ---
    k_zero_i32<<<blocks(N, B), B, 0, stream>>>(cnt, N);
    k_zero_i32<<<blocks(N, B), B, 0, stream>>>(cursor, N);
    k_count<<<blocks(E, B), B, 0, stream>>>(col, E, cnt);
    k_scan<<<1, 1024, 0, stream>>>(cnt, starts, N);
    k_dinv<<<blocks(N, B), B, 0, stream>>>(starts, dinv, N);
    k_fill<<<blocks(E, B), B, 0, stream>>>(row, col, E, starts, cursor, csr);

    const bool fast = (K0 == 64 && F1 == 128 && F2 == 128 && F3 == 64);

    if (fast) {
        // --- layer 1: x[N,64] @ W1[64,128] ---
        k_gemm_t<64, 128, 64><<<blocks(N, 64), 256, 0, stream>>>(x, W1, P, N);
        k_aggregate4<128><<<blocks(N, 8), 256, 0, stream>>>(P, starts, csr, dinv, b1, H, N, 1);
        // --- layer 2: H[N,128] @ W2[128,128] ---
        k_gemm_t<128, 128, 64><<<blocks(N, 64), 256, 0, stream>>>(H, W2, P, N);
        k_aggregate4<128><<<blocks(N, 8), 256, 0, stream>>>(P, starts, csr, dinv, b2, H, N, 1);
        // --- layer 3: H[N,128] @ W3[128,64] ---
        k_gemm_t<128, 64, 128><<<blocks(N, 128), 256, 0, stream>>>(H, W3, P, N);
        k_aggregate4<64><<<blocks(N, 16), 256, 0, stream>>>(P, starts, csr, dinv, b3, H, N, 0);
    } else {
        k_gemm_naive<<<blocks((long)N * F1, B), B, 0, stream>>>(x, W1, P, N, K0, F1);
        k_aggregate4<128><<<blocks(N, 8), 256, 0, stream>>>(P, starts, csr, dinv, b1, H, N, 1);
        k_gemm_naive<<<blocks((long)N * F2, B), B, 0, stream>>>(H, W2, P, N, F1, F2);
        k_aggregate4<128><<<blocks(N, 8), 256, 0, stream>>>(P, starts, csr, dinv, b2, H, N, 1);
        k_gemm_naive<<<blocks((long)N * F3, B), B, 0, stream>>>(H, W3, P, N, F2, F3);
        k_aggregate4<64><<<blocks(N, 16), 256, 0, stream>>>(P, starts, csr, dinv, b3, H, N, 0);
    }

    // --- pool + final ---
    k_pool<<<Gn, F3, 0, stream>>>(H, batch, N, F3, pooled);
    k_final<<<blocks(Gn * C, B), B, 0, stream>>>(pooled, Wl, bl, (float*)d_out, Gn, F3, C);
}

// Round 5
// 312.216 us; speedup vs baseline: 4.6591x; 1.4239x over previous
//
#include <hip/hip_runtime.h>
#include <hip/hip_fp16.h>

// ---------------- utility kernels ----------------

__global__ void k_zero_i32(int* __restrict__ p, int n) {
    int i = blockIdx.x * blockDim.x + threadIdx.x;
    if (i < n) p[i] = 0;
}

__global__ void k_count(const int* __restrict__ col, int E, int* __restrict__ cnt) {
    int e = blockIdx.x * blockDim.x + threadIdx.x;
    if (e < E) atomicAdd(&cnt[col[e]], 1);
}

// ---- 3-pass parallel exclusive scan over cnt[0..N) -> starts[0..N] ----
// pass 1: per-1024-chunk sums
__global__ void k_bsum(const int* __restrict__ cnt, int N, int* __restrict__ bsum) {
    __shared__ int wt[4];
    int t = threadIdx.x;
    int i0 = blockIdx.x * 1024 + t * 4;
    int s = 0;
    #pragma unroll
    for (int j = 0; j < 4; ++j) { int i = i0 + j; if (i < N) s += cnt[i]; }
    #pragma unroll
    for (int off = 32; off > 0; off >>= 1) s += __shfl_down(s, off, 64);
    if ((t & 63) == 0) wt[t >> 6] = s;
    __syncthreads();
    if (t == 0) bsum[blockIdx.x] = wt[0] + wt[1] + wt[2] + wt[3];
}

// pass 2: single-wave exclusive scan of bsum[nb]; also starts[N] = total
__global__ void k_bscan(int* __restrict__ bsum, int nb, int* __restrict__ starts, int N) {
    int lane = threadIdx.x;
    int carry = 0;
    for (int base = 0; base < nb; base += 64) {
        int i = base + lane;
        int v = (i < nb) ? bsum[i] : 0;
        int s = v;
        #pragma unroll
        for (int off = 1; off < 64; off <<= 1) {
            int u = __shfl_up(s, off, 64);
            if (lane >= off) s += u;
        }
        if (i < nb) bsum[i] = carry + s - v;
        carry += __shfl(s, 63, 64);
    }
    if (lane == 0) starts[N] = carry;
}

// pass 3: rescan chunk + chunk offset -> exclusive starts
__global__ void k_scan_apply(const int* __restrict__ cnt, const int* __restrict__ bsum,
                             int* __restrict__ starts, int N) {
    __shared__ int wt[4];
    int t = threadIdx.x;
    int lane = t & 63;
    int w = t >> 6;
    int i0 = blockIdx.x * 1024 + t * 4;
    int v[4];
    int ts = 0;
    #pragma unroll
    for (int j = 0; j < 4; ++j) { int i = i0 + j; v[j] = (i < N) ? cnt[i] : 0; ts += v[j]; }
    int s = ts;
    #pragma unroll
    for (int off = 1; off < 64; off <<= 1) {
        int u = __shfl_up(s, off, 64);
        if (lane >= off) s += u;
    }
    if (lane == 63) wt[w] = s;
    __syncthreads();
    int woff = 0;
    if (w > 0) woff = wt[0];
    if (w > 1) woff += wt[1];
    if (w > 2) woff += wt[2];
    int base = bsum[blockIdx.x] + woff + (s - ts);
    int run = base;
    #pragma unroll
    for (int j = 0; j < 4; ++j) { int i = i0 + j; if (i < N) starts[i] = run; run += v[j]; }
}

__global__ void k_dinv(const int* __restrict__ starts, float* __restrict__ dinv, int N) {
    int i = blockIdx.x * blockDim.x + threadIdx.x;
    if (i < N) dinv[i] = rsqrtf((float)(starts[i + 1] - starts[i]) + 1.0f);
}

// fill CSR using cnt as down-counting cursor (cnt ends at zero)
__global__ void k_fill(const int* __restrict__ row, const int* __restrict__ col, int E,
                       const int* __restrict__ starts, int* __restrict__ cnt,
                       int* __restrict__ csr) {
    int e = blockIdx.x * blockDim.x + threadIdx.x;
    if (e >= E) return;
    int c = col[e];
    int pos = starts[c] + atomicSub(&cnt[c], 1) - 1;
    csr[pos] = row[e];
}

// x fp32 -> fp16
__global__ void k_f2h(const float* __restrict__ src, __half* __restrict__ dst, long n) {
    long i = ((long)blockIdx.x * blockDim.x + threadIdx.x) * 4;
    if (i + 3 < n) {
        float4 v = *(const float4*)&src[i];
        __half2 h0 = __floats2half2_rn(v.x, v.y);
        __half2 h1 = __floats2half2_rn(v.z, v.w);
        uint2 q; q.x = *(unsigned int*)&h0; q.y = *(unsigned int*)&h1;
        *(uint2*)&dst[i] = q;
    } else {
        for (long j = i; j < n; ++j) dst[j] = __float2half_rn(src[j]);
    }
}

// ---------------- tiled fp32 GEMM, templated output ----------------
// P[n,m] = sum_k X[n,k] * W[k,m]; thread tile TN=4 x TM=8

template<typename OT, int K, int M, int BN, bool BIAS, bool RELU>
__global__ void k_gemm_t(const float* __restrict__ X, const float* __restrict__ W,
                         OT* __restrict__ P, const float* __restrict__ bias, int N) {
    constexpr int TM = 8;
    constexpr int TN = 4;
    constexpr int TMN = M / TM;
    constexpr int TNN = BN / TN;
    constexpr int NT = TMN * TNN;
    constexpr int KC = 64;
    constexpr int MH = M / 2;
    constexpr int XLD = KC + 1;
    __shared__ float Wl[KC * M];
    __shared__ float Xl[BN * XLD];
    const int t = threadIdx.x;
    const int tm = t % TMN;
    const int tn = t / TMN;
    const int n0 = blockIdx.x * BN;
    float acc[TN][TM] = {};
    for (int k0 = 0; k0 < K; k0 += KC) {
        #pragma unroll
        for (int i = t * 4; i < KC * M; i += NT * 4)
            *(float4*)&Wl[i] = *(const float4*)&W[(long)k0 * M + i];
        {
            const int kq = t % (KC / 4);
            const int nl0 = t / (KC / 4);
            constexpr int NPN = NT / (KC / 4);
            #pragma unroll
            for (int p = 0; p < BN / NPN; ++p) {
                int n = nl0 + p * NPN;
                int gn = n0 + n;
                float4 v = make_float4(0.f, 0.f, 0.f, 0.f);
                if (gn < N) v = *(const float4*)&X[(long)gn * K + k0 + kq * 4];
                float* xr = &Xl[n * XLD + kq * 4];
                xr[0] = v.x; xr[1] = v.y; xr[2] = v.z; xr[3] = v.w;
            }
        }
        __syncthreads();
        #pragma unroll 4
        for (int k = 0; k < KC; ++k) {
            float4 w0 = *(float4*)&Wl[k * M + tm * 4];
            float4 w1 = *(float4*)&Wl[k * M + MH + tm * 4];
            float xs[TN];
            #pragma unroll
            for (int i = 0; i < TN; ++i) xs[i] = Xl[(tn * TN + i) * XLD + k];
            #pragma unroll
            for (int i = 0; i < TN; ++i) {
                acc[i][0] += xs[i] * w0.x;
                acc[i][1] += xs[i] * w0.y;
                acc[i][2] += xs[i] * w0.z;
                acc[i][3] += xs[i] * w0.w;
                acc[i][4] += xs[i] * w1.x;
                acc[i][5] += xs[i] * w1.y;
                acc[i][6] += xs[i] * w1.z;
                acc[i][7] += xs[i] * w1.w;
            }
        }
        __syncthreads();
    }
    float4 bb0 = make_float4(0.f, 0.f, 0.f, 0.f), bb1 = bb0;
    if (BIAS) {
        bb0 = *(const float4*)&bias[tm * 4];
        bb1 = *(const float4*)&bias[MH + tm * 4];
    }
    #pragma unroll
    for (int i = 0; i < TN; ++i) {
        int gn = n0 + tn * TN + i;
        if (gn >= N) continue;
        float4 a0 = make_float4(acc[i][0], acc[i][1], acc[i][2], acc[i][3]);
        float4 a1 = make_float4(acc[i][4], acc[i][5], acc[i][6], acc[i][7]);
        if (BIAS) {
            a0.x += bb0.x; a0.y += bb0.y; a0.z += bb0.z; a0.w += bb0.w;
            a1.x += bb1.x; a1.y += bb1.y; a1.z += bb1.z; a1.w += bb1.w;
        }
        if (RELU) {
            a0.x = fmaxf(a0.x, 0.f); a0.y = fmaxf(a0.y, 0.f);
            a0.z = fmaxf(a0.z, 0.f); a0.w = fmaxf(a0.w, 0.f);
            a1.x = fmaxf(a1.x, 0.f); a1.y = fmaxf(a1.y, 0.f);
            a1.z = fmaxf(a1.z, 0.f); a1.w = fmaxf(a1.w, 0.f);
        }
        if constexpr (__is_same(OT, float)) {
            *(float4*)&P[(long)gn * M + tm * 4] = a0;
            *(float4*)&P[(long)gn * M + MH + tm * 4] = a1;
        } else {
            __half2 h0 = __floats2half2_rn(a0.x, a0.y);
            __half2 h1 = __floats2half2_rn(a0.z, a0.w);
            __half2 h2 = __floats2half2_rn(a1.x, a1.y);
            __half2 h3 = __floats2half2_rn(a1.z, a1.w);
            uint2 q0; q0.x = *(unsigned int*)&h0; q0.y = *(unsigned int*)&h1;
            uint2 q1; q1.x = *(unsigned int*)&h2; q1.y = *(unsigned int*)&h3;
            *(uint2*)&P[(long)gn * M + tm * 4] = q0;
            *(uint2*)&P[(long)gn * M + MH + tm * 4] = q1;
        }
    }
}

// ---------------- fp16-gather aggregation ----------------
// H[c,f] = relu?( dinv[c]*sum_{r} P16[r,f]*dinv[r] + dinv[c]^2*P16[c,f] (+ b[f]) )
// lane covers 8 features (16 B per gathered row-slice)

template<int M, bool BIAS, bool RELU>
__global__ void k_agg16(const __half* __restrict__ P16, const int* __restrict__ starts,
                        const int* __restrict__ csr, const float* __restrict__ dinv,
                        const float* __restrict__ b, float* __restrict__ H, int N) {
    constexpr int TPN = M / 8;
    constexpr int NPB = 256 / TPN;
    int local = threadIdx.x / TPN;
    int fq = threadIdx.x % TPN;
    int f0 = fq * 8;
    int c = blockIdx.x * NPB + local;
    if (c >= N) return;
    int s = starts[c], e = starts[c + 1];
    float acc[8] = {};
    int i = s;
    for (; i + 1 < e; i += 2) {
        int r0 = csr[i], r1 = csr[i + 1];
        float d0 = dinv[r0], d1 = dinv[r1];
        uint4 u0 = *(const uint4*)&P16[(long)r0 * M + f0];
        uint4 u1 = *(const uint4*)&P16[(long)r1 * M + f0];
        const __half2* h0 = (const __half2*)&u0;
        const __half2* h1 = (const __half2*)&u1;
        #pragma unroll
        for (int j = 0; j < 4; ++j) {
            float2 f0v = __half22float2(h0[j]);
            float2 f1v = __half22float2(h1[j]);
            acc[2 * j]     += f0v.x * d0 + f1v.x * d1;
            acc[2 * j + 1] += f0v.y * d0 + f1v.y * d1;
        }
    }
    if (i < e) {
        int r0 = csr[i];
        float d0 = dinv[r0];
        uint4 u0 = *(const uint4*)&P16[(long)r0 * M + f0];
        const __half2* h0 = (const __half2*)&u0;
        #pragma unroll
        for (int j = 0; j < 4; ++j) {
            float2 f0v = __half22float2(h0[j]);
            acc[2 * j]     += f0v.x * d0;
            acc[2 * j + 1] += f0v.y * d0;
        }
    }
    float dc = dinv[c];
    float dc2 = dc * dc;
    uint4 us = *(const uint4*)&P16[(long)c * M + f0];
    const __half2* hs = (const __half2*)&us;
    float v[8];
    #pragma unroll
    for (int j = 0; j < 4; ++j) {
        float2 fs = __half22float2(hs[j]);
        v[2 * j]     = dc * acc[2 * j]     + dc2 * fs.x;
        v[2 * j + 1] = dc * acc[2 * j + 1] + dc2 * fs.y;
    }
    if (BIAS) {
        float4 bb0 = *(const float4*)&b[f0];
        float4 bb1 = *(const float4*)&b[f0 + 4];
        v[0] += bb0.x; v[1] += bb0.y; v[2] += bb0.z; v[3] += bb0.w;
        v[4] += bb1.x; v[5] += bb1.y; v[6] += bb1.z; v[7] += bb1.w;
    }
    if (RELU) {
        #pragma unroll
        for (int j = 0; j < 8; ++j) v[j] = fmaxf(v[j], 0.f);
    }
    *(float4*)&H[(long)c * M + f0]     = make_float4(v[0], v[1], v[2], v[3]);
    *(float4*)&H[(long)c * M + f0 + 4] = make_float4(v[4], v[5], v[6], v[7]);
}

// ---------------- fp32 fallback kernels (unexpected shapes) ----------------

__global__ void k_gemm_naive(const float* __restrict__ X, const float* __restrict__ W,
                             float* __restrict__ P, int N, int K, int M) {
    long idx = (long)blockIdx.x * blockDim.x + threadIdx.x;
    long total = (long)N * M;
    if (idx >= total) return;
    int n = (int)(idx / M);
    int m = (int)(idx - (long)n * M);
    const float* xr = X + (long)n * K;
    float acc = 0.0f;
    for (int k = 0; k < K; ++k) acc += xr[k] * W[k * M + m];
    P[idx] = acc;
}

template<int M>
__global__ void k_aggregate4(const float* __restrict__ P, const int* __restrict__ starts,
                             const int* __restrict__ csr, const float* __restrict__ dinv,
                             const float* __restrict__ b, float* __restrict__ H,
                             int N, int do_relu) {
    constexpr int TPN = M / 4;
    constexpr int NPB = 256 / TPN;
    int local = threadIdx.x / TPN;
    int fq = threadIdx.x % TPN;
    int c = blockIdx.x * NPB + local;
    if (c >= N) return;
    int s = starts[c], e = starts[c + 1];
    float4 acc = make_float4(0.f, 0.f, 0.f, 0.f);
    for (int i = s; i < e; ++i) {
        int r = csr[i];
        float dr = dinv[r];
        float4 p = *(const float4*)&P[(long)r * M + fq * 4];
        acc.x += p.x * dr; acc.y += p.y * dr; acc.z += p.z * dr; acc.w += p.w * dr;
    }
    float dc = dinv[c];
    float dc2 = dc * dc;
    float4 ps = *(const float4*)&P[(long)c * M + fq * 4];
    float4 bb = *(const float4*)&b[fq * 4];
    float4 v;
    v.x = dc * acc.x + dc2 * ps.x + bb.x;
    v.y = dc * acc.y + dc2 * ps.y + bb.y;
    v.z = dc * acc.z + dc2 * ps.z + bb.z;
    v.w = dc * acc.w + dc2 * ps.w + bb.w;
    if (do_relu) {
        v.x = fmaxf(v.x, 0.f); v.y = fmaxf(v.y, 0.f);
        v.z = fmaxf(v.z, 0.f); v.w = fmaxf(v.w, 0.f);
    }
    *(float4*)&H[(long)c * M + fq * 4] = v;
}

// ---------------- pooling + classifier ----------------

__device__ __forceinline__ int lower_bound_i(const int* __restrict__ a, int n, int key) {
    int lo = 0, hi = n;
    while (lo < hi) { int mid = (lo + hi) >> 1; if (a[mid] < key) lo = mid + 1; else hi = mid; }
    return lo;
}

__global__ void k_pool(const float* __restrict__ H, const int* __restrict__ batch,
                       int N, int M, float* __restrict__ pooled) {
    int g = blockIdx.x;
    int f = threadIdx.x;       // blockDim.x == M
    int lo = lower_bound_i(batch, N, g);
    int hi = lower_bound_i(batch, N, g + 1);
    float acc = 0.0f;
    for (int n = lo; n < hi; ++n) acc += H[(long)n * M + f];
    float inv = 1.0f / fmaxf((float)(hi - lo), 1.0f);
    pooled[(long)g * M + f] = acc * inv;
}

__global__ void k_final(const float* __restrict__ pooled, const float* __restrict__ Wl,
                        const float* __restrict__ bl, float* __restrict__ out,
                        int Gn, int F, int C) {
    int idx = blockIdx.x * blockDim.x + threadIdx.x;
    if (idx >= Gn * C) return;
    int g = idx / C;
    int j = idx - g * C;
    float acc = bl[j];
    for (int f = 0; f < F; ++f) acc += pooled[g * F + f] * Wl[f * C + j];
    out[idx] = acc;
}

// ---------------- launch ----------------

extern "C" void kernel_launch(void* const* d_in, const int* in_sizes, int n_in,
                              void* d_out, int out_size, void* d_ws, size_t ws_size,
                              hipStream_t stream) {
    const float* x  = (const float*)d_in[0];
    const int*   ei = (const int*)d_in[1];
    const int*   batch = (const int*)d_in[2];
    const float* W1 = (const float*)d_in[3];
    const float* b1 = (const float*)d_in[4];
    const float* W2 = (const float*)d_in[5];
    const float* b2 = (const float*)d_in[6];
    const float* W3 = (const float*)d_in[7];
    const float* b3 = (const float*)d_in[8];
    const float* Wl = (const float*)d_in[9];
    const float* bl = (const float*)d_in[10];

    const int N  = in_sizes[2];          // 50000
    const int E  = in_sizes[1] / 2;      // 800000
    const int C  = in_sizes[10];         // 10
    const int Gn = out_size / C;         // 512
    const int F1 = in_sizes[4];          // 128
    const int F2 = in_sizes[6];          // 128
    const int F3 = in_sizes[8];          // 64
    const int K0 = in_sizes[0] / N;      // 64

    const int* row = ei;
    const int* col = ei + E;

    // workspace layout (same footprint as R2: ~55 MB)
    int* cnt    = (int*)d_ws;                 // N
    int* starts = cnt + N;                    // N+1
    int* bsum   = starts + N + 1;             // 256
    int* csr    = bsum + 256;                 // E
    float* dinv = (float*)(csr + E);          // N
    float* A    = dinv + N;                   // N*128 f32
    float* B    = A + (long)N * 128;          // N*128 f32
    float* pooled = B + (long)N * 128;        // Gn*64

    // aliases inside A (time-disjoint)
    float*  AX   = A;                               // [N,64] f32
    __half* X16  = (__half*)(A + (long)N * 64);     // [N,64] f16
    __half* P16a = (__half*)A;                      // [N,128] f16
    __half* P16b = (__half*)A;                      // [N,64] f16 (lower quarter)
    float*  H3   = A + (long)N * 64;                // [N,64] f32

    const int BLK = 256;
    auto blocks = [](long n, int b) { return (int)((n + b - 1) / b); };
    const int nb = blocks(N, 1024);

    // --- build CSR ---
    k_zero_i32<<<blocks(N, BLK), BLK, 0, stream>>>(cnt, N);
    k_count<<<blocks(E, BLK), BLK, 0, stream>>>(col, E, cnt);
    k_bsum<<<nb, 256, 0, stream>>>(cnt, N, bsum);
    k_bscan<<<1, 64, 0, stream>>>(bsum, nb, starts, N);
    k_scan_apply<<<nb, 256, 0, stream>>>(cnt, bsum, starts, N);
    k_dinv<<<blocks(N, BLK), BLK, 0, stream>>>(starts, dinv, N);
    k_fill<<<blocks(E, BLK), BLK, 0, stream>>>(row, col, E, starts, cnt, csr);

    const bool fast = (K0 == 64 && F1 == 128 && F2 == 128 && F3 == 64);

    if (fast) {
        // --- layer 1 (reordered): H1 = relu( (A_hat X) W1 + b1 ) ---
        k_f2h<<<blocks(((long)N * 64 + 3) / 4, BLK), BLK, 0, stream>>>(x, X16, (long)N * 64);
        k_agg16<64, false, false><<<blocks(N, 32), 256, 0, stream>>>(X16, starts, csr, dinv, nullptr, AX, N);
        k_gemm_t<float, 64, 128, 64, true, true><<<blocks(N, 64), 256, 0, stream>>>(AX, W1, B, b1, N);
        // --- layer 2: H2 = relu( A_hat (H1 W2) + b2 ) ---
        k_gemm_t<__half, 128, 128, 64, false, false><<<blocks(N, 64), 256, 0, stream>>>(B, W2, P16a, nullptr, N);
        k_agg16<128, true, true><<<blocks(N, 16), 256, 0, stream>>>(P16a, starts, csr, dinv, b2, B, N);
        // --- layer 3: H3 = A_hat (H2 W3) + b3 ---
        k_gemm_t<__half, 128, 64, 128, false, false><<<blocks(N, 128), 256, 0, stream>>>(B, W3, P16b, nullptr, N);
        k_agg16<64, true, false><<<blocks(N, 32), 256, 0, stream>>>(P16b, starts, csr, dinv, b3, H3, N);
        // --- pool + final ---
        k_pool<<<Gn, F3, 0, stream>>>(H3, batch, N, F3, pooled);
    } else {
        k_gemm_naive<<<blocks((long)N * F1, BLK), BLK, 0, stream>>>(x, W1, A, N, K0, F1);
        k_aggregate4<128><<<blocks(N, 8), 256, 0, stream>>>(A, starts, csr, dinv, b1, B, N, 1);
        k_gemm_naive<<<blocks((long)N * F2, BLK), BLK, 0, stream>>>(B, W2, A, N, F1, F2);
        k_aggregate4<128><<<blocks(N, 8), 256, 0, stream>>>(A, starts, csr, dinv, b2, B, N, 1);
        k_gemm_naive<<<blocks((long)N * F3, BLK), BLK, 0, stream>>>(B, W3, A, N, F2, F3);
        k_aggregate4<64><<<blocks(N, 16), 256, 0, stream>>>(A, starts, csr, dinv, b3, B, N, 0);
        k_pool<<<Gn, F3, 0, stream>>>(B, batch, N, F3, pooled);
    }

    k_final<<<blocks(Gn * C, BLK), BLK, 0, stream>>>(pooled, Wl, bl, (float*)d_out, Gn, F3, C);
}